// Round 5
// baseline (175.819 us; speedup 1.0000x reference)
//
#include <hip/hip_runtime.h>
#include <math.h>

#define C 100
#define INV_NORM 0.3989422804014327f   // 1/sqrt(2*pi), STD = 1
#define WFAR     0.67102943f           // exp(-inv_norm) = lim_{|d|->oo} w(d)

// w'(a) = exp(code(a)-inv_norm) - wfar, code(a) = inv_norm*exp(-a^2/2).
// Zero for a >= 7 (w'(6) ~ 4e-9). Table padded to 16 (|d| <= 15 at edges).
__device__ __constant__ float WP_dev[8] = {
    0.32897057f, 0.18369895f, 0.03722540f, 0.00298049f,
    8.9804e-5f,  9.9763e-7f,  4.0768e-9f,  0.f };

// quad (4-lane) sum via DPP quad_perm — VALU only, no DS pipe
__device__ __forceinline__ float quad_sum(float x) {
    x += __int_as_float(__builtin_amdgcn_update_dpp(
            0, __float_as_int(x), 0xB1, 0xF, 0xF, true));  // [1,0,3,2]
    x += __int_as_float(__builtin_amdgcn_update_dpp(
            0, __float_as_int(x), 0x4E, 0xF, 0xF, true));  // [2,3,0,1]
    return x;
}

// One quad per row, rows loaded straight into registers.
// Quad-strided float4 loads: per wave-instr, 16 quads x one 64B line = 16
// lines — same TA cost as a fully coalesced 1KB load. No LDS staging.
// kl_row = (dotc - dot)/csum - inv_norm - log(csum) + log(sum_j exp s_j)
//   dot  = wfar*rowsum + sum_{|d|<=6} w'(d) s_{mu+d}   (13-elem window)
//   csum = 100*wfar + sum_{valid d} w'(|d|)            (literals, edge-masked)
//   dotc = sum_{valid d} w(|d|)*code(|d|)
// (scores ~ N(0,1): exp(s) safe in fp32 without max-subtraction)
__global__ __launch_bounds__(256) void kl_main(
    const float* __restrict__ scores,
    const int*   __restrict__ labels,
    float* __restrict__ out, int n, float inv_n)
{
    __shared__ float wq[16];
    __shared__ float wpart[4];

    const int tid = threadIdx.x;
    if (tid < 16) wq[tid] = (tid < 8) ? WP_dev[tid] : 0.f;
    __syncthreads();

    const int wave = tid >> 6, lane = tid & 63;
    const int r = lane >> 2, sub = lane & 3;         // quad r owns row r
    const int myrow = blockIdx.x * 64 + wave * 16 + r;

    float acc = 0.f;
    if (myrow < n) {
        const float4* rp4 = (const float4*)(scores + (size_t)myrow * C);
        const int mu = labels[myrow];

        // row = 25 float4s; lane sub takes indices {sub+4i}: 6 each + idx 24 on sub==0
        float4 v[6];
        #pragma unroll
        for (int c = 0; c < 6; ++c) v[c] = rp4[sub + 4 * c];
        float4 v6 = make_float4(0.f, 0.f, 0.f, 0.f);
        if (sub == 0) v6 = rp4[24];

        // window re-read: 16 aligned elems covering [mu-6, mu+6] (L1/MSHR hit)
        const int bf = min(max(mu - 6, 0) >> 2, 21);
        const float4 wv = rp4[bf + sub];

        float se = 0.f, rs = 0.f;
        #pragma unroll
        for (int c = 0; c < 6; ++c) {
            se += __expf(v[c].x) + __expf(v[c].y) + __expf(v[c].z) + __expf(v[c].w);
            rs += v[c].x + v[c].y + v[c].z + v[c].w;
        }
        if (sub == 0) {
            se += __expf(v6.x) + __expf(v6.y) + __expf(v6.z) + __expf(v6.w);
            rs += v6.x + v6.y + v6.z + v6.w;
        }

        // window dot partial: <=16 distinct LDS addrs in 16 banks -> conflict-free
        float p = 0.f;
        {
            const int jb = 4 * (bf + sub);
            const float el[4] = {wv.x, wv.y, wv.z, wv.w};
            #pragma unroll
            for (int cmp = 0; cmp < 4; ++cmp) {
                int d = jb + cmp - mu;
                int a = d < 0 ? -d : d;          // <= 15 by construction
                p = fmaf(wq[a], el[cmp], p);
            }
        }
        p = fmaf(WFAR, rs, p);       // per-lane partial of dot

        se = quad_sum(se);
        p  = quad_sum(p);

        if (sub == 0) {
            constexpr float WPc[7] = {0.32897057f, 0.18369895f, 0.03722540f,
                0.00298049f, 8.9804e-5f, 9.9763e-7f, 4.0768e-9f};
            constexpr float WCc[7] = {0.39894228f, 0.20681926f, 0.03823936f,
                0.00298711f, 8.9816e-5f, 9.9765e-7f, 4.0768e-9f};
            float csum = 100.f * WFAR, dotc = 0.f;
            #pragma unroll
            for (int k = 0; k < 13; ++k) {
                const int d = k - 6, a = d < 0 ? -d : d;   // a compile-time
                const bool ok = (unsigned)(mu + d) < (unsigned)C;
                csum += ok ? WPc[a] : 0.f;
                dotc += ok ? WCc[a] : 0.f;
            }
            const float rcs = __builtin_amdgcn_rcpf(csum);
            acc = fmaf(dotc - p, rcs, __logf(se) - __logf(csum)) - INV_NORM;
        }
    }

    // wave reduce (only sub==0 lanes nonzero) + block combine, 1 atomic/block
    #pragma unroll
    for (int off = 32; off > 0; off >>= 1)
        acc += __shfl_xor(acc, off, 64);
    if (lane == 0) wpart[wave] = acc;
    __syncthreads();
    if (tid == 0)
        atomicAdd(out, (wpart[0] + wpart[1] + wpart[2] + wpart[3]) * inv_n);
}

extern "C" void kernel_launch(void* const* d_in, const int* in_sizes, int n_in,
                              void* d_out, int out_size, void* d_ws, size_t ws_size,
                              hipStream_t stream)
{
    const float* scores = (const float*)d_in[0];
    const int*   labels = (const int*)d_in[1];
    float*       out    = (float*)d_out;

    int n = in_sizes[0] / C;   // 262144

    // d_out is poisoned (0xAA) before every timed launch — zero it first.
    hipMemsetAsync(d_out, 0, sizeof(float) * (size_t)out_size, stream);

    int blocks = (n + 63) / 64;   // 64 rows/block -> 4096 blocks
    kl_main<<<blocks, 256, 0, stream>>>(scores, labels, out, n, 1.0f / (float)n);
}

// Round 6
// 155.876 us; speedup vs baseline: 1.1279x; 1.1279x over previous
//
#include <hip/hip_runtime.h>
#include <math.h>

#define C 100
#define RPP 16                         // rows per pass per wave
#define WAVES 4                        // waves per 256-thread block
#define PASSES 4                       // passes per wave (register dbuf'd)
#define ROWS_PER_WAVE  (RPP * PASSES)           // 64
#define ROWS_PER_BLOCK (WAVES * ROWS_PER_WAVE)  // 256
#define NF4P (RPP * C / 4)             // 400 float4 per pass
#define INV_NORM 0.3989422804014327f   // 1/sqrt(2*pi), STD = 1
#define WFAR     0.67102943f           // exp(-inv_norm) = lim w(d)

// quad (4-lane) sum via DPP quad_perm — VALU only, no DS pipe
__device__ __forceinline__ float quad_sum(float x) {
    x += __int_as_float(__builtin_amdgcn_update_dpp(
            0, __float_as_int(x), 0xB1, 0xF, 0xF, true));  // [1,0,3,2]
    x += __int_as_float(__builtin_amdgcn_update_dpp(
            0, __float_as_int(x), 0x4E, 0xF, 0xF, true));  // [2,3,0,1]
    return x;
}

// Math (verified rounds 4/5): w(d) = exp(code(d)-inv_norm),
// code(d) = inv_norm*exp(-d^2/2); w'(d) = w(d)-wfar, zero for |d|>6.
//   csum = 100*wfar + sum_{valid d} w'(|d|)
//   dot  = wfar*rowsum + sum_{|d|<=6} w'(d) s_{mu+d}
//   dotc = sum_{valid d} w(|d|)*code(|d|)
//   kl_row = (dotc - dot)/csum - inv_norm - log(csum) + log(sum_j exp s_j)
// (scores ~ N(0,1): exp(s) safe in fp32 without max-subtraction)
//
// Pipeline: per wave, register double-buffer va/vb; loads for pass p+1 are
// issued BEFORE pass p is consumed, so 7-14 coalesced loads stay in flight
// continuously. Wave-private LDS slice, no __syncthreads in the hot path
// (per-wave DS ops are in-order -> single buffer is safe). launch_bounds
// (256,4): 4 blocks/CU x 256 CU = 1024 blocks = whole grid co-resident.
__global__ __launch_bounds__(256, 4) void kl_main(
    const float* __restrict__ scores,
    const int*   __restrict__ labels,
    float* __restrict__ out, int n, float inv_n)
{
    __shared__ float sl[WAVES][RPP * C];   // 4 x 6400 B, wave-private
    __shared__ float wpart[WAVES];

    const int tid  = threadIdx.x;
    const int wave = tid >> 6, lane = tid & 63;
    const int r    = lane >> 2, sub  = lane & 3;   // quad r owns row r
    float* const mys = sl[wave];

    const int waveRow0 = blockIdx.x * ROWS_PER_BLOCK + wave * ROWS_PER_WAVE;

    float4 va[7], vb[7];
    int mua = 0, mub = 0;
    float acc = 0.f;

    auto issue = [&](float4* v, int p, int& mu) {
        const int rowBase = waveRow0 + p * RPP;
        const int nf4 = min(RPP, max(0, n - rowBase)) * (C / 4);
        const float4* g = (const float4*)(scores + (size_t)rowBase * C);
        #pragma unroll
        for (int c = 0; c < 7; ++c) {
            int i = lane + 64 * c;
            v[c] = (i < nf4) ? g[i] : make_float4(0.f, 0.f, 0.f, 0.f);
        }
        int myrow = rowBase + r;
        mu = (myrow < n) ? labels[myrow] : 0;
    };

    auto consume = [&](const float4* v, int p, int mu) {
        // stage to wave-private LDS; compiler waits only on v's loads
        float4* st = (float4*)mys;
        #pragma unroll
        for (int c = 0; c < 7; ++c) {
            int i = lane + 64 * c;
            if (i < NF4P) st[i] = v[c];
        }
        const float* sp  = &mys[r * C];
        const float* spl = sp + sub * 25;   // 2 lanes/bank: free
        float se = 0.f, rs = 0.f;
        #pragma unroll
        for (int i = 0; i < 25; ++i) {
            float s = spl[i];
            se += __expf(s);
            rs += s;
        }
        se = quad_sum(se);
        rs = quad_sum(rs);

        // 13-term window around mu, redundantly on all 4 lanes (broadcasts)
        const float WP[7] = {0.32897057f, 0.18369895f, 0.03722540f,
            0.00298049f, 8.9804e-5f, 9.9763e-7f, 4.0768e-9f};
        const float WC[7] = {0.39894228f, 0.20681926f, 0.03823936f,
            0.00298711f, 8.9816e-5f, 9.9765e-7f, 4.0768e-9f};
        float dotw = 0.f, csum = 100.f * WFAR, dotc = 0.f;
        #pragma unroll
        for (int d = -6; d <= 6; ++d) {
            int idx  = mu + d;
            bool ok  = (unsigned)idx < (unsigned)C;
            float s  = sp[min(max(idx, 0), C - 1)];
            int a    = d < 0 ? -d : d;               // compile-time
            float wv = ok ? WP[a] : 0.f;
            dotw  = fmaf(wv, s, dotw);
            csum += wv;
            dotc += ok ? WC[a] : 0.f;
        }

        int myrow = waveRow0 + p * RPP + r;
        if (sub == 0 && myrow < n) {
            float dot = fmaf(WFAR, rs, dotw);
            acc += (dotc - dot) / csum - INV_NORM - __logf(csum) + __logf(se);
        }
    };

    // software pipeline: always one pass of loads ahead
    issue(va, 0, mua);
    issue(vb, 1, mub);
    consume(va, 0, mua);
    issue(va, 2, mua);
    consume(vb, 1, mub);
    issue(vb, 3, mub);
    consume(va, 2, mua);
    consume(vb, 3, mub);

    // wave reduce (only sub==0 lanes nonzero) + block combine, 1 atomic/block
    #pragma unroll
    for (int off = 32; off > 0; off >>= 1)
        acc += __shfl_xor(acc, off, 64);
    if (lane == 0) wpart[wave] = acc;
    __syncthreads();
    if (tid == 0)
        atomicAdd(out, (wpart[0] + wpart[1] + wpart[2] + wpart[3]) * inv_n);
}

extern "C" void kernel_launch(void* const* d_in, const int* in_sizes, int n_in,
                              void* d_out, int out_size, void* d_ws, size_t ws_size,
                              hipStream_t stream)
{
    const float* scores = (const float*)d_in[0];
    const int*   labels = (const int*)d_in[1];
    float*       out    = (float*)d_out;

    int n = in_sizes[0] / C;   // 262144

    // d_out is poisoned (0xAA) before every timed launch — zero it first.
    hipMemsetAsync(d_out, 0, sizeof(float) * (size_t)out_size, stream);

    int blocks = (n + ROWS_PER_BLOCK - 1) / ROWS_PER_BLOCK;   // 1024
    kl_main<<<blocks, 256, 0, stream>>>(scores, labels, out, n, 1.0f / (float)n);
}